// Round 2
// baseline (864.741 us; speedup 1.0000x reference)
//
#include <hip/hip_runtime.h>

#define Bv   1024
#define Tv   128
#define Hv   128
#define INv  8
#define NQv  8
#define NVLv 4

// ---- cross-lane helpers: DPP for xor1/xor2, ds_swizzle for 4/8/16, shfl for 32
template<int CTRL>
__device__ __forceinline__ float dppx(float x) {
  return __int_as_float(__builtin_amdgcn_update_dpp(0, __float_as_int(x), CTRL, 0xF, 0xF, true));
}
template<int M>
__device__ __forceinline__ float lane_xor(float x) {
  if constexpr (M == 1)       return dppx<0xB1>(x);           // quad_perm [1,0,3,2]
  else if constexpr (M == 2)  return dppx<0x4E>(x);           // quad_perm [2,3,0,1]
  else if constexpr (M == 32) return __shfl_xor(x, 32, 64);
  else return __int_as_float(__builtin_amdgcn_ds_swizzle(__float_as_int(x), (M << 10) | 0x1F));
}
__device__ __forceinline__ float bperm(int addr, float x) {
  return __int_as_float(__builtin_amdgcn_ds_bpermute(addr, __float_as_int(x)));
}
__device__ __forceinline__ float fast_rcp(float x){ return __builtin_amdgcn_rcpf(x); }
__device__ __forceinline__ float fast_rsq(float x){ return __builtin_amdgcn_rsqf(x); }
__device__ __forceinline__ float tanh_(float x){
  float e = __expf(2.0f * x);
  return 1.0f - 2.0f * fast_rcp(e + 1.0f);
}
__device__ __forceinline__ float sigm_(float x){
  return fast_rcp(1.0f + __expf(-x));
}

// RY on qubit Q. idx = reg*16 + lane4. qubit q maps to idx bit (7-q):
// q0..q3 -> reg bits 3..0 (in-register pairs); q4..q7 -> lane bits 3..0 (xor 8/4/2/1)
template<int Q>
__device__ __forceinline__ void ry_gate(float* s, float cc, float ss, int lane4) {
  if constexpr (Q < 4) {
    constexpr int st = 8 >> Q;
    #pragma unroll
    for (int r = 0; r < 16; r++) {
      if ((r & st) == 0) {
        float a0 = s[r], a1 = s[r | st];
        s[r]      = fmaf(cc, a0, -(ss * a1));
        s[r | st] = fmaf(ss, a0,  (cc * a1));
      }
    }
  } else {
    constexpr int m = 8 >> (Q - 4);
    float ssn = (lane4 & m) ? ss : -ss;
    #pragma unroll
    for (int r = 0; r < 16; r++) {
      float o = lane_xor<m>(s[r]);
      s[r] = fmaf(cc, s[r], ssn * o);
    }
  }
}

struct __align__(16) SMem {
  float cs[4][68];   // per gate: (cos,sin) of wq[l][q]*0.5 at [(l*8+q)*2]
  float ipb[8][4];   // (ip_b, in_g, in_b, 0) per o
  float fbuf[16];    // encode factors f[q][bit] = cos(th/2) -/+ sin(th/2)
  float zbuf[32];    // z[gate][qubit]
};

__global__ __launch_bounds__(64, 1) void qlstm_kernel(
    const float* __restrict__ x,     const float* __restrict__ pe,
    const float* __restrict__ emb_w, const float* __restrict__ emb_b,
    const float* __restrict__ emb_g, const float* __restrict__ emb_bt,
    const float* __restrict__ ip_w,  const float* __restrict__ ip_b,
    const float* __restrict__ in_g,  const float* __restrict__ in_b,
    const float* __restrict__ wq_i,  const float* __restrict__ wq_f,
    const float* __restrict__ wq_gt, const float* __restrict__ wq_o,
    const float* __restrict__ pi_w,  const float* __restrict__ pi_b,
    const float* __restrict__ pf_w,  const float* __restrict__ pf_b,
    const float* __restrict__ pg_w,  const float* __restrict__ pg_b,
    const float* __restrict__ po_w,  const float* __restrict__ po_b,
    const float* __restrict__ on_g,  const float* __restrict__ on_b,
    const float* __restrict__ out_w, const float* __restrict__ out_b,
    float* __restrict__ out)
{
  __shared__ SMem sm;
  const int L = threadIdx.x;
  const int b = blockIdx.x;
  const int lane4 = L & 15;
  const int g = L >> 4;

  // ---- stage variational (cos,sin) table: 4 gates x 4 layers x 8 qubits
  #pragma unroll
  for (int half = 0; half < 2; half++) {
    int e = L + half * 64;          // 0..127
    int gg = e >> 5, rem = e & 31;  // rem = l*8+q
    const float* w = (gg == 0) ? wq_i : (gg == 1) ? wq_f : (gg == 2) ? wq_gt : wq_o;
    float th = w[rem] * 0.5f;
    sm.cs[gg][rem * 2]     = __cosf(th);
    sm.cs[gg][rem * 2 + 1] = __sinf(th);
  }
  if (L < 8) {
    sm.ipb[L][0] = ip_b[L];
    sm.ipb[L][1] = in_g[L];
    sm.ipb[L][2] = in_b[L];
    sm.ipb[L][3] = 0.0f;
  }
  __syncthreads();

  // ---- persistent per-lane weights (rows j0=L, j1=L+64)
  const int j0 = L, j1 = L + 64;
  float ew0[8], ew1[8];
  {
    float4 a = *reinterpret_cast<const float4*>(emb_w + j0 * 8);
    float4 c = *reinterpret_cast<const float4*>(emb_w + j0 * 8 + 4);
    ew0[0]=a.x; ew0[1]=a.y; ew0[2]=a.z; ew0[3]=a.w; ew0[4]=c.x; ew0[5]=c.y; ew0[6]=c.z; ew0[7]=c.w;
    float4 d = *reinterpret_cast<const float4*>(emb_w + j1 * 8);
    float4 e = *reinterpret_cast<const float4*>(emb_w + j1 * 8 + 4);
    ew1[0]=d.x; ew1[1]=d.y; ew1[2]=d.z; ew1[3]=d.w; ew1[4]=e.x; ew1[5]=e.y; ew1[6]=e.z; ew1[7]=e.w;
  }
  float ebb0 = emb_b[j0],  ebb1 = emb_b[j1];
  float egg0 = emb_g[j0],  egg1 = emb_g[j1];
  float ebt0 = emb_bt[j0], ebt1 = emb_bt[j1];
  float ipw[8][4];
  #pragma unroll
  for (int o = 0; o < 8; o++) {
    ipw[o][0] = ip_w[o * 256 + L];
    ipw[o][1] = ip_w[o * 256 + 64 + L];
    ipw[o][2] = ip_w[o * 256 + 128 + L];
    ipw[o][3] = ip_w[o * 256 + 192 + L];
  }
  float gw0[4][8], gw1[4][8];
  #pragma unroll
  for (int gg = 0; gg < 4; gg++) {
    const float* pw = (gg == 0) ? pi_w : (gg == 1) ? pf_w : (gg == 2) ? pg_w : po_w;
    float4 a = *reinterpret_cast<const float4*>(pw + j0 * 8);
    float4 c = *reinterpret_cast<const float4*>(pw + j0 * 8 + 4);
    gw0[gg][0]=a.x; gw0[gg][1]=a.y; gw0[gg][2]=a.z; gw0[gg][3]=a.w;
    gw0[gg][4]=c.x; gw0[gg][5]=c.y; gw0[gg][6]=c.z; gw0[gg][7]=c.w;
    float4 d = *reinterpret_cast<const float4*>(pw + j1 * 8);
    float4 e = *reinterpret_cast<const float4*>(pw + j1 * 8 + 4);
    gw1[gg][0]=d.x; gw1[gg][1]=d.y; gw1[gg][2]=d.z; gw1[gg][3]=d.w;
    gw1[gg][4]=e.x; gw1[gg][5]=e.y; gw1[gg][6]=e.z; gw1[gg][7]=e.w;
  }
  float gb0[4] = {pi_b[j0], pf_b[j0], pg_b[j0], po_b[j0]};
  float gb1[4] = {pi_b[j1], pf_b[j1], pg_b[j1], po_b[j1]};
  float ong0 = on_g[j0], ong1 = on_g[j1];
  float onb0 = on_b[j0], onb1 = on_b[j1];
  float ow0 = out_w[j0], ow1 = out_w[j1];
  float outb = out_b[0];

  // CNOT composed-permutation bpermute addresses (byte addr = srclane*4)
  const int aEven = (L ^ ((L & 8) ? 4 : 0) ^ ((L & 2) ? 1 : 0)) << 2; // c4 then c6
  const int aOddE = (L ^ ((L & 4) ? 2 : 0)) << 2;                     // c5 (even regs)
  const int aOddO = aOddE ^ 32;                                       // c3 then c5 (odd regs)

  const float* csg = sm.cs[g];
  float h0 = 0.f, h1 = 0.f, c0 = 0.f, c1 = 0.f;

  #pragma unroll 1
  for (int t = 0; t < Tv; t++) {
    // ================= embedding: LN(x@emb_w.T + emb_b)*g+bt + pe =================
    float xt[8];
    {
      const float* xp = x + ((size_t)b * Tv + t) * 8;
      float4 a = *reinterpret_cast<const float4*>(xp);
      float4 c = *reinterpret_cast<const float4*>(xp + 4);
      xt[0]=a.x; xt[1]=a.y; xt[2]=a.z; xt[3]=a.w; xt[4]=c.x; xt[5]=c.y; xt[6]=c.z; xt[7]=c.w;
    }
    float e0 = ebb0, e1 = ebb1;
    #pragma unroll
    for (int k = 0; k < 8; k++) { e0 = fmaf(xt[k], ew0[k], e0); e1 = fmaf(xt[k], ew1[k], e1); }
    {
      float s1 = e0 + e1, s2 = e0 * e0 + e1 * e1;
      s1 += lane_xor<1>(s1);  s2 += lane_xor<1>(s2);
      s1 += lane_xor<2>(s1);  s2 += lane_xor<2>(s2);
      s1 += lane_xor<4>(s1);  s2 += lane_xor<4>(s2);
      s1 += lane_xor<8>(s1);  s2 += lane_xor<8>(s2);
      s1 += lane_xor<16>(s1); s2 += lane_xor<16>(s2);
      s1 += lane_xor<32>(s1); s2 += lane_xor<32>(s2);
      float mn = s1 * 0.0078125f;
      float vr = fmaf(s2, 0.0078125f, -mn * mn);
      float inv = fast_rsq(vr + 1e-5f);
      float pe0 = pe[t * 128 + L], pe1 = pe[t * 128 + 64 + L];
      e0 = (e0 - mn) * inv * egg0 + ebt0 + pe0;
      e1 = (e1 - mn) * inv * egg1 + ebt1 + pe1;
    }

    // ================= proj = LN(tanh([e,h] @ ip_w.T + ip_b)) -> angle factors =================
    float p_[8];
    #pragma unroll
    for (int o = 0; o < 8; o++)
      p_[o] = e0 * ipw[o][0] + e1 * ipw[o][1] + h0 * ipw[o][2] + h1 * ipw[o][3];
    // merged transpose-reduce: lane ends with full dot for o = L&7
    const int bb0 = L & 1, bb1 = L & 2, bb2 = L & 4;
    float q_[4];
    #pragma unroll
    for (int k = 0; k < 4; k++) {
      float keep = bb0 ? p_[2 * k + 1] : p_[2 * k];
      float send = bb0 ? p_[2 * k]     : p_[2 * k + 1];
      q_[k] = keep + lane_xor<1>(send);
    }
    float r_[2];
    #pragma unroll
    for (int k = 0; k < 2; k++) {
      float keep = bb1 ? q_[2 * k + 1] : q_[2 * k];
      float send = bb1 ? q_[2 * k]     : q_[2 * k + 1];
      r_[k] = keep + lane_xor<2>(send);
    }
    float u;
    {
      float keep = bb2 ? r_[1] : r_[0];
      float send = bb2 ? r_[0] : r_[1];
      u = keep + lane_xor<4>(send);
    }
    u += lane_xor<8>(u); u += lane_xor<16>(u); u += lane_xor<32>(u);

    const int o8 = L & 7;
    float4 ipbv = *reinterpret_cast<float4*>(&sm.ipb[o8][0]);
    float tv = tanh_(u + ipbv.x);
    float m1 = tv, m2 = tv * tv;
    m1 += lane_xor<1>(m1); m2 += lane_xor<1>(m2);
    m1 += lane_xor<2>(m1); m2 += lane_xor<2>(m2);
    m1 += lane_xor<4>(m1); m2 += lane_xor<4>(m2);
    float pm = m1 * 0.125f;
    float pv = fmaf(m2, 0.125f, -pm * pm);
    float theta = (tv - pm) * fast_rsq(pv + 1e-5f) * ipbv.y + ipbv.z;
    float ph = theta * 0.5f;
    float cE = __cosf(ph), sE = __sinf(ph);
    if (L < 8) { sm.fbuf[2 * L] = cE - sE; sm.fbuf[2 * L + 1] = cE + sE; }
    __syncthreads();
    float f_[16];
    {
      float4 a0 = *reinterpret_cast<float4*>(&sm.fbuf[0]);
      float4 a1 = *reinterpret_cast<float4*>(&sm.fbuf[4]);
      float4 a2 = *reinterpret_cast<float4*>(&sm.fbuf[8]);
      float4 a3 = *reinterpret_cast<float4*>(&sm.fbuf[12]);
      f_[0]=a0.x; f_[1]=a0.y; f_[2]=a0.z; f_[3]=a0.w;
      f_[4]=a1.x; f_[5]=a1.y; f_[6]=a1.z; f_[7]=a1.w;
      f_[8]=a2.x; f_[9]=a2.y; f_[10]=a2.z; f_[11]=a2.w;
      f_[12]=a3.x; f_[13]=a3.y; f_[14]=a3.z; f_[15]=a3.w;
    }

    // ================= VQC (4 gates in parallel, 16 lanes each) =================
    // encode: product state  amp(idx) = (1/16) * prod_q f_q(bit_q(idx))
    float s_[16];
    {
      float g01_[4], g23_[4];
      #pragma unroll
      for (int i = 0; i < 4; i++) {
        g01_[i] = f_[(i >> 1) & 1] * f_[2 + (i & 1)];
        g23_[i] = f_[4 + ((i >> 1) & 1)] * f_[6 + (i & 1)];
      }
      float lf = f_[8 + ((lane4 >> 3) & 1)] * f_[10 + ((lane4 >> 2) & 1)]
               * f_[12 + ((lane4 >> 1) & 1)] * f_[14 + (lane4 & 1)];
      lf *= 0.0625f;
      #pragma unroll
      for (int r = 0; r < 16; r++) s_[r] = lf * g01_[r >> 2] * g23_[r & 3];
    }

    #pragma unroll
    for (int l = 0; l < NVLv; l++) {
      // CNOT even pass c=0,2 (register renames), c=4 o c=6 (one bpermute)
      { float tp;
        tp=s_[8];  s_[8]=s_[12];  s_[12]=tp;
        tp=s_[9];  s_[9]=s_[13];  s_[13]=tp;
        tp=s_[10]; s_[10]=s_[14]; s_[14]=tp;
        tp=s_[11]; s_[11]=s_[15]; s_[15]=tp;
        tp=s_[2];  s_[2]=s_[3];   s_[3]=tp;
        tp=s_[6];  s_[6]=s_[7];   s_[7]=tp;
        tp=s_[10]; s_[10]=s_[11]; s_[11]=tp;
        tp=s_[14]; s_[14]=s_[15]; s_[15]=tp;
      }
      #pragma unroll
      for (int r = 0; r < 16; r++) s_[r] = bperm(aEven, s_[r]);
      // CNOT odd pass c=1 (rename), c=3 o c=5 (one bpermute, parity-dependent addr)
      { float tp;
        tp=s_[4];  s_[4]=s_[6];   s_[6]=tp;
        tp=s_[5];  s_[5]=s_[7];   s_[7]=tp;
        tp=s_[12]; s_[12]=s_[14]; s_[14]=tp;
        tp=s_[13]; s_[13]=s_[15]; s_[15]=tp;
      }
      #pragma unroll
      for (int r = 0; r < 16; r++) s_[r] = bperm((r & 1) ? aOddO : aOddE, s_[r]);
      // RY round with this gate's layer weights
      #define RYL(Q) { float2 cs2 = *reinterpret_cast<const float2*>(&csg[(l * 8 + Q) * 2]); \
                       ry_gate<Q>(s_, cs2.x, cs2.y, lane4); }
      RYL(0) RYL(1) RYL(2) RYL(3) RYL(4) RYL(5) RYL(6) RYL(7)
      #undef RYL
    }

    // ================= measure z_q = sum_idx sign(bit) * amp^2 =================
    float p2[16];
    #pragma unroll
    for (int r = 0; r < 16; r++) p2[r] = s_[r] * s_[r];
    float aa[8]; float z0 = 0.f;
    #pragma unroll
    for (int i = 0; i < 8; i++) { aa[i] = p2[i] + p2[i + 8]; z0 += (p2[i] - p2[i + 8]); }
    float cc4[4]; float z1 = 0.f;
    #pragma unroll
    for (int i = 0; i < 4; i++) { cc4[i] = aa[i] + aa[i + 4]; z1 += (aa[i] - aa[i + 4]); }
    float ee0 = cc4[0] + cc4[2], ee1 = cc4[1] + cc4[3];
    float z2 = (cc4[0] + cc4[1]) - (cc4[2] + cc4[3]);
    float z3 = ee0 - ee1;
    float S  = ee0 + ee1;
    z0 += lane_xor<1>(z0); z0 += lane_xor<2>(z0); z0 += lane_xor<4>(z0); z0 += lane_xor<8>(z0);
    z1 += lane_xor<1>(z1); z1 += lane_xor<2>(z1); z1 += lane_xor<4>(z1); z1 += lane_xor<8>(z1);
    z2 += lane_xor<1>(z2); z2 += lane_xor<2>(z2); z2 += lane_xor<4>(z2); z2 += lane_xor<8>(z2);
    z3 += lane_xor<1>(z3); z3 += lane_xor<2>(z3); z3 += lane_xor<4>(z3); z3 += lane_xor<8>(z3);
    float v8 = lane_xor<8>(S), u8 = S + v8, d8 = S - v8;
    float z4 = (lane4 & 8) ? -d8 : d8;
    z4 += lane_xor<4>(z4); z4 += lane_xor<2>(z4); z4 += lane_xor<1>(z4);
    float v4 = lane_xor<4>(u8), u84 = u8 + v4, d4 = u8 - v4;
    float z5 = (lane4 & 4) ? -d4 : d4;
    z5 += lane_xor<2>(z5); z5 += lane_xor<1>(z5);
    float v2 = lane_xor<2>(u84), u842 = u84 + v2, d2 = u84 - v2;
    float z6 = (lane4 & 2) ? -d2 : d2;
    z6 += lane_xor<1>(z6);
    float v1 = lane_xor<1>(u842), d1 = u842 - v1;
    float z7 = (lane4 & 1) ? -d1 : d1;

    // exchange z across gate groups through LDS
    if (lane4 < 8) {
      float zv = z0;
      zv = (lane4 == 1) ? z1 : zv;
      zv = (lane4 == 2) ? z2 : zv;
      zv = (lane4 == 3) ? z3 : zv;
      zv = (lane4 == 4) ? z4 : zv;
      zv = (lane4 == 5) ? z5 : zv;
      zv = (lane4 == 6) ? z6 : zv;
      zv = (lane4 == 7) ? z7 : zv;
      sm.zbuf[g * 8 + lane4] = zv;
    }
    __syncthreads();
    float za[32];
    #pragma unroll
    for (int i = 0; i < 8; i++) {
      float4 v = *reinterpret_cast<float4*>(&sm.zbuf[i * 4]);
      za[i * 4 + 0] = v.x; za[i * 4 + 1] = v.y; za[i * 4 + 2] = v.z; za[i * 4 + 3] = v.w;
    }

    // ================= gate projections + LSTM cell =================
    float acc0[4], acc1[4];
    #pragma unroll
    for (int gg = 0; gg < 4; gg++) {
      float a0v = gb0[gg], a1v = gb1[gg];
      #pragma unroll
      for (int qq = 0; qq < 8; qq++) {
        float zq = za[gg * 8 + qq];
        a0v = fmaf(zq, gw0[gg][qq], a0v);
        a1v = fmaf(zq, gw1[gg][qq], a1v);
      }
      acc0[gg] = a0v; acc1[gg] = a1v;
    }
    float it0 = sigm_(acc0[0]), ft0 = sigm_(acc0[1]), gt0 = tanh_(acc0[2]), ot0 = sigm_(acc0[3]);
    float it1 = sigm_(acc1[0]), ft1 = sigm_(acc1[1]), gt1 = tanh_(acc1[2]), ot1 = sigm_(acc1[3]);
    c0 = ft0 * c0 + it0 * gt0;
    c1 = ft1 * c1 + it1 * gt1;
    h0 = ot0 * tanh_(c0);
    h1 = ot1 * tanh_(c1);

    // ================= out_t = LN(h + e) ; y = out_t @ out_w + out_b =================
    float y0 = h0 + e0, y1 = h1 + e1;
    float t1s = y0 + y1, t2s = y0 * y0 + y1 * y1;
    t1s += lane_xor<1>(t1s);  t2s += lane_xor<1>(t2s);
    t1s += lane_xor<2>(t1s);  t2s += lane_xor<2>(t2s);
    t1s += lane_xor<4>(t1s);  t2s += lane_xor<4>(t2s);
    t1s += lane_xor<8>(t1s);  t2s += lane_xor<8>(t2s);
    t1s += lane_xor<16>(t1s); t2s += lane_xor<16>(t2s);
    t1s += lane_xor<32>(t1s); t2s += lane_xor<32>(t2s);
    float mn2 = t1s * 0.0078125f;
    float vr2 = fmaf(t2s, 0.0078125f, -mn2 * mn2);
    float inv2 = fast_rsq(vr2 + 1e-5f);
    float oo0 = (y0 - mn2) * inv2 * ong0 + onb0;
    float oo1 = (y1 - mn2) * inv2 * ong1 + onb1;
    float dt = oo0 * ow0 + oo1 * ow1;
    dt += lane_xor<1>(dt); dt += lane_xor<2>(dt); dt += lane_xor<4>(dt);
    dt += lane_xor<8>(dt); dt += lane_xor<16>(dt); dt += lane_xor<32>(dt);
    if (L == 0) out[b * Tv + t] = dt + outb;
  }
}

extern "C" void kernel_launch(void* const* d_in, const int* in_sizes, int n_in,
                              void* d_out, int out_size, void* d_ws, size_t ws_size,
                              hipStream_t stream) {
  qlstm_kernel<<<dim3(Bv), dim3(64), 0, stream>>>(
      (const float*)d_in[0],  (const float*)d_in[1],  (const float*)d_in[2],  (const float*)d_in[3],
      (const float*)d_in[4],  (const float*)d_in[5],  (const float*)d_in[6],  (const float*)d_in[7],
      (const float*)d_in[8],  (const float*)d_in[9],  (const float*)d_in[10], (const float*)d_in[11],
      (const float*)d_in[12], (const float*)d_in[13], (const float*)d_in[14], (const float*)d_in[15],
      (const float*)d_in[16], (const float*)d_in[17], (const float*)d_in[18], (const float*)d_in[19],
      (const float*)d_in[20], (const float*)d_in[21], (const float*)d_in[22], (const float*)d_in[23],
      (const float*)d_in[24], (const float*)d_in[25],
      (float*)d_out);
}

// Round 3
// 784.233 us; speedup vs baseline: 1.1027x; 1.1027x over previous
//
#include <hip/hip_runtime.h>

#define Tv 128

// ---- cross-lane helpers: DPP for xor1/xor2, ds_swizzle for 4/8/16 (within 32), shfl for 32
template<int CTRL>
__device__ __forceinline__ float dppx(float x) {
  return __int_as_float(__builtin_amdgcn_update_dpp(0, __float_as_int(x), CTRL, 0xF, 0xF, true));
}
template<int M>
__device__ __forceinline__ float lane_xor(float x) {
  if constexpr (M == 1)       return dppx<0xB1>(x);           // quad_perm [1,0,3,2]
  else if constexpr (M == 2)  return dppx<0x4E>(x);           // quad_perm [2,3,0,1]
  else if constexpr (M == 32) return __shfl_xor(x, 32, 64);
  else return __int_as_float(__builtin_amdgcn_ds_swizzle(__float_as_int(x), (M << 10) | 0x1F));
}
__device__ __forceinline__ float bperm(int addr, float x) {
  return __int_as_float(__builtin_amdgcn_ds_bpermute(addr, __float_as_int(x)));
}
__device__ __forceinline__ float fast_rcp(float x){ return __builtin_amdgcn_rcpf(x); }
__device__ __forceinline__ float fast_rsq(float x){ return __builtin_amdgcn_rsqf(x); }
__device__ __forceinline__ float tanh_(float x){
  float e = __expf(2.0f * x);
  return 1.0f - 2.0f * fast_rcp(e + 1.0f);
}
__device__ __forceinline__ float sigm_(float x){
  return fast_rcp(1.0f + __expf(-x));
}

// State: 256 amps = 8 regs x 32 lanes. idx = reg(3b, idx bits 7..5) | lane5(5b, idx bits 4..0).
// Qubit q <-> idx bit (7-q): q0..q2 -> reg bits 2..0; q3..q7 -> lane bits 4..0 (masks 16,8,4,2,1).
template<int Q>
__device__ __forceinline__ void ry8(float* s, float cc, float ss, int l5) {
  if constexpr (Q < 3) {
    constexpr int st = 4 >> Q;   // Q0->4, Q1->2, Q2->1
    #pragma unroll
    for (int r = 0; r < 8; r++) {
      if ((r & st) == 0) {
        float a0 = s[r], a1 = s[r | st];
        s[r]      = fmaf(cc, a0, -(ss * a1));
        s[r | st] = fmaf(ss, a0,  (cc * a1));
      }
    }
  } else {
    constexpr int m = 16 >> (Q - 3);  // Q3->16, Q4->8, Q5->4, Q6->2, Q7->1
    float ssn = (l5 & m) ? ss : -ss;
    #pragma unroll
    for (int r = 0; r < 8; r++) {
      float o = lane_xor<m>(s[r]);
      s[r] = fmaf(cc, s[r], ssn * o);
    }
  }
}

struct __align__(16) SMem {
  float cs[4][66];    // per gate: (cos,sin) at [(l*8+q)*2]; stride 66 staggers banks
  float ipb[8][4];    // (ip_b, in_g, in_b, 0)
  float fbuf[2][16];  // per-wave encode factors (same-wave RAW, no barrier)
  float zbuf[32];     // z[gate][qubit] (cross-wave)
  float embp[2][4];   // emb-LN partials
  float projp[2][8];  // proj partials
  float outp[2][4];   // out-epilogue partials (also init SW/KB reduce)
};

__global__ __launch_bounds__(128, 2) void qlstm_kernel(
    const float* __restrict__ x,     const float* __restrict__ pe,
    const float* __restrict__ emb_w, const float* __restrict__ emb_b,
    const float* __restrict__ emb_g, const float* __restrict__ emb_bt,
    const float* __restrict__ ip_w,  const float* __restrict__ ip_b,
    const float* __restrict__ in_g,  const float* __restrict__ in_b,
    const float* __restrict__ wq_i,  const float* __restrict__ wq_f,
    const float* __restrict__ wq_gt, const float* __restrict__ wq_o,
    const float* __restrict__ pi_w,  const float* __restrict__ pi_b,
    const float* __restrict__ pf_w,  const float* __restrict__ pf_b,
    const float* __restrict__ pg_w,  const float* __restrict__ pg_b,
    const float* __restrict__ po_w,  const float* __restrict__ po_b,
    const float* __restrict__ on_g,  const float* __restrict__ on_b,
    const float* __restrict__ out_w, const float* __restrict__ out_b,
    float* __restrict__ out)
{
  __shared__ SMem sm;
  const int tid = threadIdx.x;          // 0..127 = row j
  const int b   = blockIdx.x;
  const int w   = tid >> 6;             // wave id 0/1
  const int L   = tid & 63;             // lane in wave
  const int l5  = L & 31;               // lane within gate group
  const int gate = w * 2 + (L >> 5);    // 0..3 = i,f,g,o
  const int o8  = L & 7;

  // ---- stage (cos,sin) for variational layers: 4 gates x 32 (l*8+q) entries
  {
    int gg = tid >> 5, rem = tid & 31;
    const float* wsel = (gg == 0) ? wq_i : (gg == 1) ? wq_f : (gg == 2) ? wq_gt : wq_o;
    float th = wsel[rem] * 0.5f;
    sm.cs[gg][rem * 2]     = __cosf(th);
    sm.cs[gg][rem * 2 + 1] = __sinf(th);
  }
  if (tid < 8) {
    sm.ipb[tid][0] = ip_b[tid];
    sm.ipb[tid][1] = in_g[tid];
    sm.ipb[tid][2] = in_b[tid];
    sm.ipb[tid][3] = 0.0f;
  }
  __syncthreads();

  // ---- persistent per-thread (row j = tid) weights
  const int j = tid;
  float ew[8];
  {
    float4 a = *reinterpret_cast<const float4*>(emb_w + j * 8);
    float4 c = *reinterpret_cast<const float4*>(emb_w + j * 8 + 4);
    ew[0]=a.x; ew[1]=a.y; ew[2]=a.z; ew[3]=a.w; ew[4]=c.x; ew[5]=c.y; ew[6]=c.z; ew[7]=c.w;
  }
  float ebb = emb_b[j], egg = emb_g[j], ebt = emb_bt[j];
  float ipw1[8], ipw2[8];
  #pragma unroll
  for (int o = 0; o < 8; o++) {
    ipw1[o] = ip_w[o * 256 + j];
    ipw2[o] = ip_w[o * 256 + 128 + j];
  }
  float gw[4][8];
  #pragma unroll
  for (int gg = 0; gg < 4; gg++) {
    const float* pw = (gg == 0) ? pi_w : (gg == 1) ? pf_w : (gg == 2) ? pg_w : po_w;
    float4 a = *reinterpret_cast<const float4*>(pw + j * 8);
    float4 c = *reinterpret_cast<const float4*>(pw + j * 8 + 4);
    gw[gg][0]=a.x; gw[gg][1]=a.y; gw[gg][2]=a.z; gw[gg][3]=a.w;
    gw[gg][4]=c.x; gw[gg][5]=c.y; gw[gg][6]=c.z; gw[gg][7]=c.w;
  }
  float gb[4] = {pi_b[j], pf_b[j], pg_b[j], po_b[j]};
  float ong = on_g[j], onb = on_b[j], ow_ = out_w[j];
  float outb = out_b[0];
  float a_ = ong * ow_;                 // per-row weight for fused epilogue

  // ---- precompute SW = sum(on_g*out_w), KB = sum(on_b*out_w) + out_b (block reduce once)
  float SW, KB;
  {
    float r0 = a_, r1 = onb * ow_;
    r0 += lane_xor<1>(r0);  r1 += lane_xor<1>(r1);
    r0 += lane_xor<2>(r0);  r1 += lane_xor<2>(r1);
    r0 += lane_xor<4>(r0);  r1 += lane_xor<4>(r1);
    r0 += lane_xor<8>(r0);  r1 += lane_xor<8>(r1);
    r0 += lane_xor<16>(r0); r1 += lane_xor<16>(r1);
    r0 += lane_xor<32>(r0); r1 += lane_xor<32>(r1);
    if (L == 0) { sm.outp[w][0] = r0; sm.outp[w][1] = r1; }
    __syncthreads();
    SW = sm.outp[0][0] + sm.outp[1][0];
    KB = sm.outp[0][1] + sm.outp[1][1] + outb;
  }

  // CNOT composed bpermute addresses (within own 32-lane group; byte addr = srclane*4)
  const int grp = L & 32;
  const int aEven = (grp | (l5 ^ ((l5 & 8)  ? 4 : 0) ^ ((l5 & 2) ? 1 : 0))) << 2; // c4∘c6
  const int aOdd  = (grp | (l5 ^ ((l5 & 16) ? 8 : 0) ^ ((l5 & 4) ? 2 : 0))) << 2; // c3∘c5

  const float* csg = sm.cs[gate];
  float h = 0.f, c = 0.f;

  const float* xbase = x + (size_t)b * Tv * 8;
  float xt[8], pec;
  {
    float4 a = *reinterpret_cast<const float4*>(xbase);
    float4 cq = *reinterpret_cast<const float4*>(xbase + 4);
    xt[0]=a.x; xt[1]=a.y; xt[2]=a.z; xt[3]=a.w; xt[4]=cq.x; xt[5]=cq.y; xt[6]=cq.z; xt[7]=cq.w;
    pec = pe[j];
  }

  #pragma unroll 1
  for (int t = 0; t < Tv; t++) {
    // ---- embedding row: e_j = x_t . ew + ebb
    float e = ebb;
    #pragma unroll
    for (int k = 0; k < 8; k++) e = fmaf(xt[k], ew[k], e);

    // prefetch next step's x row + pe
    float xn[8], pen;
    {
      int tn = (t + 1) & (Tv - 1);
      float4 a = *reinterpret_cast<const float4*>(xbase + tn * 8);
      float4 cq = *reinterpret_cast<const float4*>(xbase + tn * 8 + 4);
      xn[0]=a.x; xn[1]=a.y; xn[2]=a.z; xn[3]=a.w; xn[4]=cq.x; xn[5]=cq.y; xn[6]=cq.z; xn[7]=cq.w;
      pen = pe[tn * 128 + j];
    }

    // ---- LN over 128 rows (block reduce)
    {
      float s1 = e, s2 = e * e;
      s1 += lane_xor<1>(s1);  s2 += lane_xor<1>(s2);
      s1 += lane_xor<2>(s1);  s2 += lane_xor<2>(s2);
      s1 += lane_xor<4>(s1);  s2 += lane_xor<4>(s2);
      s1 += lane_xor<8>(s1);  s2 += lane_xor<8>(s2);
      s1 += lane_xor<16>(s1); s2 += lane_xor<16>(s2);
      s1 += lane_xor<32>(s1); s2 += lane_xor<32>(s2);
      if (L == 0) { sm.embp[w][0] = s1; sm.embp[w][1] = s2; }
      __syncthreads();
      s1 = sm.embp[0][0] + sm.embp[1][0];
      s2 = sm.embp[0][1] + sm.embp[1][1];
      float mn = s1 * 0.0078125f;
      float vr = fmaf(s2, 0.0078125f, -mn * mn);
      float inv = fast_rsq(vr + 1e-5f);
      e = (e - mn) * inv * egg + ebt + pec;
    }

    // ---- proj: p_o = sum_j e_j*ip_w[o][j] + h_j*ip_w[o][128+j]
    float p_[8];
    #pragma unroll
    for (int o = 0; o < 8; o++)
      p_[o] = fmaf(e, ipw1[o], h * ipw2[o]);
    // merged transpose-reduce within wave -> lane holds wave-partial for o = L&7
    const int bb0 = L & 1, bb1 = L & 2, bb2 = L & 4;
    float q_[4];
    #pragma unroll
    for (int k = 0; k < 4; k++) {
      float keep = bb0 ? p_[2 * k + 1] : p_[2 * k];
      float send = bb0 ? p_[2 * k]     : p_[2 * k + 1];
      q_[k] = keep + lane_xor<1>(send);
    }
    float r_[2];
    #pragma unroll
    for (int k = 0; k < 2; k++) {
      float keep = bb1 ? q_[2 * k + 1] : q_[2 * k];
      float send = bb1 ? q_[2 * k]     : q_[2 * k + 1];
      r_[k] = keep + lane_xor<2>(send);
    }
    float u;
    {
      float keep = bb2 ? r_[1] : r_[0];
      float send = bb2 ? r_[0] : r_[1];
      u = keep + lane_xor<4>(send);
    }
    u += lane_xor<8>(u); u += lane_xor<16>(u); u += lane_xor<32>(u);
    if (L < 8) sm.projp[w][L] = u;
    __syncthreads();
    u += sm.projp[1 - w][o8];

    // ---- angles: tanh + LN(8) -> (cos,sin) encode factors (per wave, no barrier)
    float4 ipbv = *reinterpret_cast<float4*>(&sm.ipb[o8][0]);
    float tv = tanh_(u + ipbv.x);
    float m1 = tv, m2 = tv * tv;
    m1 += lane_xor<1>(m1); m2 += lane_xor<1>(m2);
    m1 += lane_xor<2>(m1); m2 += lane_xor<2>(m2);
    m1 += lane_xor<4>(m1); m2 += lane_xor<4>(m2);
    float pm = m1 * 0.125f;
    float pv = fmaf(m2, 0.125f, -pm * pm);
    float theta = (tv - pm) * fast_rsq(pv + 1e-5f) * ipbv.y + ipbv.z;
    float ph = theta * 0.5f;
    float cE = __cosf(ph), sE = __sinf(ph);
    if (L < 8) { sm.fbuf[w][2 * L] = cE - sE; sm.fbuf[w][2 * L + 1] = cE + sE; }
    float f_[16];
    {
      float4 a0 = *reinterpret_cast<float4*>(&sm.fbuf[w][0]);
      float4 a1 = *reinterpret_cast<float4*>(&sm.fbuf[w][4]);
      float4 a2 = *reinterpret_cast<float4*>(&sm.fbuf[w][8]);
      float4 a3 = *reinterpret_cast<float4*>(&sm.fbuf[w][12]);
      f_[0]=a0.x; f_[1]=a0.y; f_[2]=a0.z; f_[3]=a0.w;
      f_[4]=a1.x; f_[5]=a1.y; f_[6]=a1.z; f_[7]=a1.w;
      f_[8]=a2.x; f_[9]=a2.y; f_[10]=a2.z; f_[11]=a2.w;
      f_[12]=a3.x; f_[13]=a3.y; f_[14]=a3.z; f_[15]=a3.w;
    }

    // ---- VQC encode: amp = (1/16) * prod_q f_q(bit)
    float s_[8];
    {
      float g01_[4];
      #pragma unroll
      for (int i = 0; i < 4; i++)
        g01_[i] = f_[(i >> 1) & 1] * f_[2 + (i & 1)];
      float lf = f_[6 + ((l5 >> 4) & 1)] * f_[8 + ((l5 >> 3) & 1)]
               * f_[10 + ((l5 >> 2) & 1)] * f_[12 + ((l5 >> 1) & 1)]
               * f_[14 + (l5 & 1)];
      lf *= 0.0625f;
      #pragma unroll
      for (int r = 0; r < 8; r++)
        s_[r] = lf * g01_[r >> 1] * f_[4 + (r & 1)];
    }

    // ---- 4 variational layers
    #pragma unroll
    for (int l = 0; l < 4; l++) {
      // even CNOTs: c0 (reg rename), c2 (reg-odd lane-xor16), c4∘c6 (bpermute)
      { float tp;
        tp = s_[4]; s_[4] = s_[6]; s_[6] = tp;
        tp = s_[5]; s_[5] = s_[7]; s_[7] = tp;
      }
      s_[1] = lane_xor<16>(s_[1]); s_[3] = lane_xor<16>(s_[3]);
      s_[5] = lane_xor<16>(s_[5]); s_[7] = lane_xor<16>(s_[7]);
      #pragma unroll
      for (int r = 0; r < 8; r++) s_[r] = bperm(aEven, s_[r]);
      // odd CNOTs: c1 (reg rename), c3∘c5 (bpermute)
      { float tp;
        tp = s_[2]; s_[2] = s_[3]; s_[3] = tp;
        tp = s_[6]; s_[6] = s_[7]; s_[7] = tp;
      }
      #pragma unroll
      for (int r = 0; r < 8; r++) s_[r] = bperm(aOdd, s_[r]);
      // RY round
      #define RYL(Q) { float2 cs2 = *reinterpret_cast<const float2*>(&csg[(l * 8 + Q) * 2]); \
                       ry8<Q>(s_, cs2.x, cs2.y, l5); }
      RYL(0) RYL(1) RYL(2) RYL(3) RYL(4) RYL(5) RYL(6) RYL(7)
      #undef RYL
    }

    // ---- measure z_q
    float p2[8];
    #pragma unroll
    for (int r = 0; r < 8; r++) p2[r] = s_[r] * s_[r];
    float aa0 = p2[0] + p2[4], aa1 = p2[1] + p2[5], aa2 = p2[2] + p2[6], aa3 = p2[3] + p2[7];
    float z0 = (p2[0] + p2[1] + p2[2] + p2[3]) - (p2[4] + p2[5] + p2[6] + p2[7]);
    float z1 = (aa0 + aa1) - (aa2 + aa3);
    float cc0 = aa0 + aa2, cc1 = aa1 + aa3;
    float z2 = cc0 - cc1;
    float S  = cc0 + cc1;
    z0 += lane_xor<1>(z0); z1 += lane_xor<1>(z1); z2 += lane_xor<1>(z2);
    z0 += lane_xor<2>(z0); z1 += lane_xor<2>(z1); z2 += lane_xor<2>(z2);
    z0 += lane_xor<4>(z0); z1 += lane_xor<4>(z1); z2 += lane_xor<4>(z2);
    z0 += lane_xor<8>(z0); z1 += lane_xor<8>(z1); z2 += lane_xor<8>(z2);
    z0 += lane_xor<16>(z0); z1 += lane_xor<16>(z1); z2 += lane_xor<16>(z2);
    float v, d, uS;
    v = lane_xor<16>(S); d = S - v; uS = S + v;
    float z3 = (l5 & 16) ? -d : d;
    z3 += lane_xor<8>(z3); z3 += lane_xor<4>(z3); z3 += lane_xor<2>(z3); z3 += lane_xor<1>(z3);
    v = lane_xor<8>(uS); d = uS - v; uS = uS + v;
    float z4 = (l5 & 8) ? -d : d;
    z4 += lane_xor<4>(z4); z4 += lane_xor<2>(z4); z4 += lane_xor<1>(z4);
    v = lane_xor<4>(uS); d = uS - v; uS = uS + v;
    float z5 = (l5 & 4) ? -d : d;
    z5 += lane_xor<2>(z5); z5 += lane_xor<1>(z5);
    v = lane_xor<2>(uS); d = uS - v; uS = uS + v;
    float z6 = (l5 & 2) ? -d : d;
    z6 += lane_xor<1>(z6);
    v = lane_xor<1>(uS); d = uS - v;
    float z7 = (l5 & 1) ? -d : d;

    // exchange z across waves
    if (l5 < 8) {
      float zv = z0;
      zv = (l5 == 1) ? z1 : zv;
      zv = (l5 == 2) ? z2 : zv;
      zv = (l5 == 3) ? z3 : zv;
      zv = (l5 == 4) ? z4 : zv;
      zv = (l5 == 5) ? z5 : zv;
      zv = (l5 == 6) ? z6 : zv;
      zv = (l5 == 7) ? z7 : zv;
      sm.zbuf[gate * 8 + l5] = zv;
    }
    __syncthreads();

    // ---- gate projections + LSTM cell (one row per thread)
    float acc[4];
    #pragma unroll
    for (int gg = 0; gg < 4; gg++) {
      float4 za0 = *reinterpret_cast<float4*>(&sm.zbuf[gg * 8]);
      float4 za1 = *reinterpret_cast<float4*>(&sm.zbuf[gg * 8 + 4]);
      float av = gb[gg];
      av = fmaf(za0.x, gw[gg][0], av); av = fmaf(za0.y, gw[gg][1], av);
      av = fmaf(za0.z, gw[gg][2], av); av = fmaf(za0.w, gw[gg][3], av);
      av = fmaf(za1.x, gw[gg][4], av); av = fmaf(za1.y, gw[gg][5], av);
      av = fmaf(za1.z, gw[gg][6], av); av = fmaf(za1.w, gw[gg][7], av);
      acc[gg] = av;
    }
    float it = sigm_(acc[0]), ft = sigm_(acc[1]), gt = tanh_(acc[2]), ot = sigm_(acc[3]);
    c = ft * c + it * gt;
    h = ot * tanh_(c);

    // ---- fused epilogue: dt = inv*(sum(y*a) - mn*SW) + KB, y = h + e
    {
      float y = h + e;
      float r0 = y, r1 = y * y, r2 = y * a_;
      r0 += lane_xor<1>(r0);  r1 += lane_xor<1>(r1);  r2 += lane_xor<1>(r2);
      r0 += lane_xor<2>(r0);  r1 += lane_xor<2>(r1);  r2 += lane_xor<2>(r2);
      r0 += lane_xor<4>(r0);  r1 += lane_xor<4>(r1);  r2 += lane_xor<4>(r2);
      r0 += lane_xor<8>(r0);  r1 += lane_xor<8>(r1);  r2 += lane_xor<8>(r2);
      r0 += lane_xor<16>(r0); r1 += lane_xor<16>(r1); r2 += lane_xor<16>(r2);
      r0 += lane_xor<32>(r0); r1 += lane_xor<32>(r1); r2 += lane_xor<32>(r2);
      if (L == 0) { sm.outp[w][0] = r0; sm.outp[w][1] = r1; sm.outp[w][2] = r2; }
      __syncthreads();
      if (tid == 0) {
        float sy  = sm.outp[0][0] + sm.outp[1][0];
        float sy2 = sm.outp[0][1] + sm.outp[1][1];
        float sya = sm.outp[0][2] + sm.outp[1][2];
        float mn2 = sy * 0.0078125f;
        float vr2 = fmaf(sy2, 0.0078125f, -mn2 * mn2);
        float inv2 = fast_rsq(vr2 + 1e-5f);
        out[b * Tv + t] = fmaf(inv2, sya - mn2 * SW, KB);
      }
    }

    #pragma unroll
    for (int k = 0; k < 8; k++) xt[k] = xn[k];
    pec = pen;
  }
}

extern "C" void kernel_launch(void* const* d_in, const int* in_sizes, int n_in,
                              void* d_out, int out_size, void* d_ws, size_t ws_size,
                              hipStream_t stream) {
  qlstm_kernel<<<dim3(1024), dim3(128), 0, stream>>>(
      (const float*)d_in[0],  (const float*)d_in[1],  (const float*)d_in[2],  (const float*)d_in[3],
      (const float*)d_in[4],  (const float*)d_in[5],  (const float*)d_in[6],  (const float*)d_in[7],
      (const float*)d_in[8],  (const float*)d_in[9],  (const float*)d_in[10], (const float*)d_in[11],
      (const float*)d_in[12], (const float*)d_in[13], (const float*)d_in[14], (const float*)d_in[15],
      (const float*)d_in[16], (const float*)d_in[17], (const float*)d_in[18], (const float*)d_in[19],
      (const float*)d_in[20], (const float*)d_in[21], (const float*)d_in[22], (const float*)d_in[23],
      (const float*)d_in[24], (const float*)d_in[25],
      (float*)d_out);
}

// Round 4
// 665.686 us; speedup vs baseline: 1.2990x; 1.1781x over previous
//
#include <hip/hip_runtime.h>

#define Tv 128

// ---- DPP / cross-lane helpers
template<int CTRL>
__device__ __forceinline__ float dppx(float x) {
  return __int_as_float(__builtin_amdgcn_update_dpp(0, __float_as_int(x), CTRL, 0xF, 0xF, true));
}
__device__ __forceinline__ float dpp_rm(float x, int ctrl, int rm) {
  switch (ctrl) {  // ctrl must be constant-foldable; callers pass literals
    default: return 0.f;
    case 0x111: return __int_as_float(__builtin_amdgcn_update_dpp(0, __float_as_int(x), 0x111, 0xF, 0xF, true));
    case 0x112: return __int_as_float(__builtin_amdgcn_update_dpp(0, __float_as_int(x), 0x112, 0xF, 0xF, true));
    case 0x114: return __int_as_float(__builtin_amdgcn_update_dpp(0, __float_as_int(x), 0x114, 0xF, 0xF, true));
    case 0x118: return __int_as_float(__builtin_amdgcn_update_dpp(0, __float_as_int(x), 0x118, 0xF, 0xF, true));
    case 0x142: return __int_as_float(__builtin_amdgcn_update_dpp(0, __float_as_int(x), 0x142, 0xA, 0xF, true));
    case 0x143: return __int_as_float(__builtin_amdgcn_update_dpp(0, __float_as_int(x), 0x143, 0xC, 0xF, true));
  }
}
// full-wave64 sum, result broadcast via readlane(63) -> uniform
__device__ __forceinline__ float wave_sum(float x) {
  x += dpp_rm(x, 0x111, 0xF);  // row_shr:1
  x += dpp_rm(x, 0x112, 0xF);  // row_shr:2
  x += dpp_rm(x, 0x114, 0xF);  // row_shr:4
  x += dpp_rm(x, 0x118, 0xF);  // row_shr:8  -> lane15/31/47/63 hold row sums
  x += dpp_rm(x, 0x142, 0xA);  // bcast15 -> rows 1,3
  x += dpp_rm(x, 0x143, 0xC);  // bcast31 -> rows 2,3; lane63 = total
  return __int_as_float(__builtin_amdgcn_readlane(__float_as_int(x), 63));
}
template<int M>
__device__ __forceinline__ float lane_xor(float x) {
  if constexpr (M == 1)       return dppx<0xB1>(x);    // quad_perm [1,0,3,2]
  else if constexpr (M == 2)  return dppx<0x4E>(x);    // quad_perm [2,3,0,1]
  else if constexpr (M == 8)  return dppx<0x128>(x);   // row_ror:8 == xor8 (VALU pipe)
  else if constexpr (M == 32) return __shfl_xor(x, 32, 64);
  else return __int_as_float(__builtin_amdgcn_ds_swizzle(__float_as_int(x), (M << 10) | 0x1F));
}
__device__ __forceinline__ float bperm(int addr, float x) {
  return __int_as_float(__builtin_amdgcn_ds_bpermute(addr, __float_as_int(x)));
}
__device__ __forceinline__ float rdlane(float x, int l) {
  return __int_as_float(__builtin_amdgcn_readlane(__float_as_int(x), l));
}
__device__ __forceinline__ float fast_rcp(float x){ return __builtin_amdgcn_rcpf(x); }
__device__ __forceinline__ float fast_rsq(float x){ return __builtin_amdgcn_rsqf(x); }
__device__ __forceinline__ float tanh_(float x){
  float e = __expf(2.0f * x);
  return 1.0f - 2.0f * fast_rcp(e + 1.0f);
}
__device__ __forceinline__ float sigm_(float x){
  return fast_rcp(1.0f + __expf(-x));
}

// State: 256 amps = 8 regs x 32 lanes. idx = reg(3b: idx bits 7..5) | l5(5b: idx bits 4..0).
// Qubit q <-> idx bit (7-q): q0..q2 -> reg bits 2..0; q3..q7 -> lane masks 16,8,4,2,1.
template<int Q>
__device__ __forceinline__ void ry8(float* s, float cc, float ss, int l5) {
  if constexpr (Q < 3) {
    constexpr int st = 4 >> Q;
    #pragma unroll
    for (int r = 0; r < 8; r++) {
      if ((r & st) == 0) {
        float a0 = s[r], a1 = s[r | st];
        s[r]      = fmaf(cc, a0, -(ss * a1));
        s[r | st] = fmaf(ss, a0,  (cc * a1));
      }
    }
  } else {
    constexpr int m = 16 >> (Q - 3);
    float ssn = (l5 & m) ? ss : -ss;
    #pragma unroll
    for (int r = 0; r < 8; r++) {
      float o = lane_xor<m>(s[r]);
      s[r] = fmaf(cc, s[r], ssn * o);
    }
  }
}

struct __align__(16) SMem {
  float cs[4][66];    // per gate: (cos,sin) at [(l*8+q)*2]
  float ipb[8][4];    // (ip_b, in_g, in_b, 0)
  float zbuf[32];     // z[gate][qubit]
  float embp[2][2];   // emb-LN partials (s1,s2)
  float projp[2][8];  // proj partials
  float outp[2][4];   // out-epilogue partials (init: SW/KB)
};

__global__ __launch_bounds__(128, 2) void qlstm_kernel(
    const float* __restrict__ x,     const float* __restrict__ pe,
    const float* __restrict__ emb_w, const float* __restrict__ emb_b,
    const float* __restrict__ emb_g, const float* __restrict__ emb_bt,
    const float* __restrict__ ip_w,  const float* __restrict__ ip_b,
    const float* __restrict__ in_g,  const float* __restrict__ in_b,
    const float* __restrict__ wq_i,  const float* __restrict__ wq_f,
    const float* __restrict__ wq_gt, const float* __restrict__ wq_o,
    const float* __restrict__ pi_w,  const float* __restrict__ pi_b,
    const float* __restrict__ pf_w,  const float* __restrict__ pf_b,
    const float* __restrict__ pg_w,  const float* __restrict__ pg_b,
    const float* __restrict__ po_w,  const float* __restrict__ po_b,
    const float* __restrict__ on_g,  const float* __restrict__ on_b,
    const float* __restrict__ out_w, const float* __restrict__ out_b,
    float* __restrict__ out)
{
  __shared__ SMem sm;
  const int tid = threadIdx.x;          // 0..127 = row j
  const int b   = blockIdx.x;
  const int w   = tid >> 6;             // wave 0/1
  const int L   = tid & 63;
  const int l5  = L & 31;
  const int gate = w * 2 + (L >> 5);    // 0..3 = i,f,g,o
  const int o8  = L & 7;

  // ---- stage (cos,sin) table
  {
    int gg = tid >> 5, rem = tid & 31;
    const float* wsel = (gg == 0) ? wq_i : (gg == 1) ? wq_f : (gg == 2) ? wq_gt : wq_o;
    float th = wsel[rem] * 0.5f;
    sm.cs[gg][rem * 2]     = __cosf(th);
    sm.cs[gg][rem * 2 + 1] = __sinf(th);
  }
  if (tid < 8) {
    sm.ipb[tid][0] = ip_b[tid];
    sm.ipb[tid][1] = in_g[tid];
    sm.ipb[tid][2] = in_b[tid];
    sm.ipb[tid][3] = 0.0f;
  }

  // ---- persistent per-thread weights (row j = tid)
  const int j = tid;
  float ew[8];
  {
    float4 a = *reinterpret_cast<const float4*>(emb_w + j * 8);
    float4 c = *reinterpret_cast<const float4*>(emb_w + j * 8 + 4);
    ew[0]=a.x; ew[1]=a.y; ew[2]=a.z; ew[3]=a.w; ew[4]=c.x; ew[5]=c.y; ew[6]=c.z; ew[7]=c.w;
  }
  float ebb = emb_b[j], egg = emb_g[j], ebt = emb_bt[j];
  float ipw1[8], ipw2[8];
  #pragma unroll
  for (int o = 0; o < 8; o++) {
    ipw1[o] = ip_w[o * 256 + j];
    ipw2[o] = ip_w[o * 256 + 128 + j];
  }
  float gw[4][8];
  #pragma unroll
  for (int gg = 0; gg < 4; gg++) {
    const float* pw = (gg == 0) ? pi_w : (gg == 1) ? pf_w : (gg == 2) ? pg_w : po_w;
    float4 a = *reinterpret_cast<const float4*>(pw + j * 8);
    float4 c = *reinterpret_cast<const float4*>(pw + j * 8 + 4);
    gw[gg][0]=a.x; gw[gg][1]=a.y; gw[gg][2]=a.z; gw[gg][3]=a.w;
    gw[gg][4]=c.x; gw[gg][5]=c.y; gw[gg][6]=c.z; gw[gg][7]=c.w;
  }
  float gb[4] = {pi_b[j], pf_b[j], pg_b[j], po_b[j]};
  float ong = on_g[j], onb = on_b[j], ow_ = out_w[j];
  float outb = out_b[0];
  float a_ = ong * ow_;

  // Composed per-layer CNOT permutation (c0..c6 folded into one bpermute round).
  // new[r, l] = old[sigR(r), l2_{pr(r)}(l)];  sigR = [0,1,3,2,6,7,5,4], pr(r) = (r^(r>>1))&1
  const int grp = L & 32;
  int aC0, aC1;
  {
    int l1 = l5 ^ ((l5 & 16) >> 1) ^ ((l5 & 4) >> 1);
    int lb = l1 ^ ((l1 & 8) >> 1) ^ ((l1 & 2) >> 1);
    aC0 = (grp | lb) << 2;
    aC1 = (grp | (lb ^ 16)) << 2;
  }

  const float* csg = sm.cs[gate];
  float h = 0.f, c = 0.f;

  const float* xbase = x + (size_t)b * Tv * 8;

  // ---- pre-loop: e_0 + SW/KB partials, single barrier
  float e;
  {
    float4 a = *reinterpret_cast<const float4*>(xbase);
    float4 cq = *reinterpret_cast<const float4*>(xbase + 4);
    float xt[8] = {a.x,a.y,a.z,a.w,cq.x,cq.y,cq.z,cq.w};
    float er = ebb;
    #pragma unroll
    for (int k = 0; k < 8; k++) er = fmaf(xt[k], ew[k], er);
    float s1 = wave_sum(er), s2 = wave_sum(er * er);
    float r0 = wave_sum(a_), r1 = wave_sum(onb * ow_);
    if (L == 0) {
      sm.embp[w][0] = s1; sm.embp[w][1] = s2;
      sm.outp[w][0] = r0; sm.outp[w][1] = r1;
    }
    __syncthreads();
    s1 = sm.embp[0][0] + sm.embp[1][0];
    s2 = sm.embp[0][1] + sm.embp[1][1];
    float mn = s1 * 0.0078125f;
    float vr = fmaf(s2, 0.0078125f, -mn * mn);
    float inv = fast_rsq(vr + 1e-5f);
    e = (er - mn) * inv * egg + ebt + pe[j];
  }
  const float SW = sm.outp[0][0] + sm.outp[1][0];
  const float KB = sm.outp[0][1] + sm.outp[1][1] + outb;

  #pragma unroll 1
  for (int t = 0; t < Tv; t++) {
    // ---- prefetch next x,pe
    float xn[8], pen;
    {
      int tn = (t + 1) & (Tv - 1);
      float4 a = *reinterpret_cast<const float4*>(xbase + tn * 8);
      float4 cq = *reinterpret_cast<const float4*>(xbase + tn * 8 + 4);
      xn[0]=a.x; xn[1]=a.y; xn[2]=a.z; xn[3]=a.w; xn[4]=cq.x; xn[5]=cq.y; xn[6]=cq.z; xn[7]=cq.w;
      pen = pe[tn * 128 + j];
    }

    // ---- proj: p_o = sum_j e_j*ipw1 + h_j*ipw2; butterfly transpose-reduce
    float p_[8];
    #pragma unroll
    for (int o = 0; o < 8; o++)
      p_[o] = fmaf(e, ipw1[o], h * ipw2[o]);
    const int bb0 = L & 1, bb1 = L & 2, bb2 = L & 4;
    float q_[4];
    #pragma unroll
    for (int k = 0; k < 4; k++) {
      float keep = bb0 ? p_[2 * k + 1] : p_[2 * k];
      float send = bb0 ? p_[2 * k]     : p_[2 * k + 1];
      q_[k] = keep + lane_xor<1>(send);
    }
    float r_[2];
    #pragma unroll
    for (int k = 0; k < 2; k++) {
      float keep = bb1 ? q_[2 * k + 1] : q_[2 * k];
      float send = bb1 ? q_[2 * k]     : q_[2 * k + 1];
      r_[k] = keep + lane_xor<2>(send);
    }
    float u;
    {
      float keep = bb2 ? r_[1] : r_[0];
      float send = bb2 ? r_[0] : r_[1];
      u = keep + lane_xor<4>(send);
    }
    u += lane_xor<8>(u); u += lane_xor<16>(u); u += lane_xor<32>(u);
    if (L < 8) sm.projp[w][L] = u;
    __syncthreads();                                  // ===== barrier 1
    u += sm.projp[1 - w][o8];
    if (t && tid == 0) {                              // emit out[t-1] (pipelined)
      float sy  = sm.outp[0][0] + sm.outp[1][0];
      float sy2 = sm.outp[0][1] + sm.outp[1][1];
      float sya = sm.outp[0][2] + sm.outp[1][2];
      float mn2 = sy * 0.0078125f;
      float vr2 = fmaf(sy2, 0.0078125f, -mn2 * mn2);
      float inv2 = fast_rsq(vr2 + 1e-5f);
      out[b * Tv + t - 1] = fmaf(inv2, sya - mn2 * SW, KB);
    }

    // ---- angles: tanh + LN(8) -> encode factors, broadcast via readlane
    float4 ipbv = *reinterpret_cast<float4*>(&sm.ipb[o8][0]);
    float tv = tanh_(u + ipbv.x);
    float m1 = tv, m2 = tv * tv;
    m1 += lane_xor<1>(m1); m2 += lane_xor<1>(m2);
    m1 += lane_xor<2>(m1); m2 += lane_xor<2>(m2);
    m1 += lane_xor<4>(m1); m2 += lane_xor<4>(m2);
    float pm = m1 * 0.125f;
    float pv = fmaf(m2, 0.125f, -pm * pm);
    float theta = (tv - pm) * fast_rsq(pv + 1e-5f) * ipbv.y + ipbv.z;
    float ph = theta * 0.5f;
    float cE = __cosf(ph), sE = __sinf(ph);
    float fm = cE - sE, fp = cE + sE;
    float f_[16];
    #pragma unroll
    for (int qq = 0; qq < 8; qq++) {
      f_[2 * qq]     = rdlane(fm, qq);
      f_[2 * qq + 1] = rdlane(fp, qq);
    }

    // ---- VQC encode
    float s_[8];
    {
      float g01_[4];
      #pragma unroll
      for (int i = 0; i < 4; i++)
        g01_[i] = f_[(i >> 1) & 1] * f_[2 + (i & 1)];
      float lf = f_[6 + ((l5 >> 4) & 1)] * f_[8 + ((l5 >> 3) & 1)]
               * f_[10 + ((l5 >> 2) & 1)] * f_[12 + ((l5 >> 1) & 1)]
               * f_[14 + (l5 & 1)];
      lf *= 0.0625f;
      #pragma unroll
      for (int r = 0; r < 8; r++)
        s_[r] = lf * g01_[r >> 1] * f_[4 + (r & 1)];
    }

    // ---- 4 variational layers: one composed bpermute + 8 RYs each
    #pragma unroll
    for (int l = 0; l < 4; l++) {
      float ns[8];
      ns[0] = bperm(aC0, s_[0]);
      ns[1] = bperm(aC1, s_[1]);
      ns[2] = bperm(aC1, s_[3]);
      ns[3] = bperm(aC0, s_[2]);
      ns[4] = bperm(aC0, s_[6]);
      ns[5] = bperm(aC1, s_[7]);
      ns[6] = bperm(aC1, s_[5]);
      ns[7] = bperm(aC0, s_[4]);
      #pragma unroll
      for (int r = 0; r < 8; r++) s_[r] = ns[r];
      #define RYL(Q) { float2 cs2 = *reinterpret_cast<const float2*>(&csg[(l * 8 + Q) * 2]); \
                       ry8<Q>(s_, cs2.x, cs2.y, l5); }
      RYL(0) RYL(1) RYL(2) RYL(3) RYL(4) RYL(5) RYL(6) RYL(7)
      #undef RYL
    }

    // ---- measure z_q
    float p2[8];
    #pragma unroll
    for (int r = 0; r < 8; r++) p2[r] = s_[r] * s_[r];
    float aa0 = p2[0] + p2[4], aa1 = p2[1] + p2[5], aa2 = p2[2] + p2[6], aa3 = p2[3] + p2[7];
    float z0 = (p2[0] + p2[1] + p2[2] + p2[3]) - (p2[4] + p2[5] + p2[6] + p2[7]);
    float z1 = (aa0 + aa1) - (aa2 + aa3);
    float cc0 = aa0 + aa2, cc1 = aa1 + aa3;
    float z2 = cc0 - cc1;
    float S  = cc0 + cc1;
    z0 += lane_xor<1>(z0); z1 += lane_xor<1>(z1); z2 += lane_xor<1>(z2);
    z0 += lane_xor<2>(z0); z1 += lane_xor<2>(z1); z2 += lane_xor<2>(z2);
    z0 += lane_xor<4>(z0); z1 += lane_xor<4>(z1); z2 += lane_xor<4>(z2);
    z0 += lane_xor<8>(z0); z1 += lane_xor<8>(z1); z2 += lane_xor<8>(z2);
    z0 += lane_xor<16>(z0); z1 += lane_xor<16>(z1); z2 += lane_xor<16>(z2);
    float v, d, uS;
    v = lane_xor<16>(S); d = S - v; uS = S + v;
    float z3 = (l5 & 16) ? -d : d;
    z3 += lane_xor<8>(z3); z3 += lane_xor<4>(z3); z3 += lane_xor<2>(z3); z3 += lane_xor<1>(z3);
    v = lane_xor<8>(uS); d = uS - v; uS = uS + v;
    float z4 = (l5 & 8) ? -d : d;
    z4 += lane_xor<4>(z4); z4 += lane_xor<2>(z4); z4 += lane_xor<1>(z4);
    v = lane_xor<4>(uS); d = uS - v; uS = uS + v;
    float z5 = (l5 & 4) ? -d : d;
    z5 += lane_xor<2>(z5); z5 += lane_xor<1>(z5);
    v = lane_xor<2>(uS); d = uS - v; uS = uS + v;
    float z6 = (l5 & 2) ? -d : d;
    z6 += lane_xor<1>(z6);
    v = lane_xor<1>(uS); d = uS - v;
    float z7 = (l5 & 1) ? -d : d;

    if (l5 < 8) {
      float zv = z0;
      zv = (l5 == 1) ? z1 : zv;
      zv = (l5 == 2) ? z2 : zv;
      zv = (l5 == 3) ? z3 : zv;
      zv = (l5 == 4) ? z4 : zv;
      zv = (l5 == 5) ? z5 : zv;
      zv = (l5 == 6) ? z6 : zv;
      zv = (l5 == 7) ? z7 : zv;
      sm.zbuf[gate * 8 + l5] = zv;
    }

    // ---- next-step emb partials (recurrence-independent; rides barrier 2)
    float en_raw = ebb;
    #pragma unroll
    for (int k = 0; k < 8; k++) en_raw = fmaf(xn[k], ew[k], en_raw);
    {
      float s1n = wave_sum(en_raw), s2n = wave_sum(en_raw * en_raw);
      if (L == 0) { sm.embp[w][0] = s1n; sm.embp[w][1] = s2n; }
    }
    __syncthreads();                                  // ===== barrier 2

    // ---- gate projections + LSTM cell
    float acc[4];
    #pragma unroll
    for (int gg = 0; gg < 4; gg++) {
      float4 za0 = *reinterpret_cast<float4*>(&sm.zbuf[gg * 8]);
      float4 za1 = *reinterpret_cast<float4*>(&sm.zbuf[gg * 8 + 4]);
      float av = gb[gg];
      av = fmaf(za0.x, gw[gg][0], av); av = fmaf(za0.y, gw[gg][1], av);
      av = fmaf(za0.z, gw[gg][2], av); av = fmaf(za0.w, gw[gg][3], av);
      av = fmaf(za1.x, gw[gg][4], av); av = fmaf(za1.y, gw[gg][5], av);
      av = fmaf(za1.z, gw[gg][6], av); av = fmaf(za1.w, gw[gg][7], av);
      acc[gg] = av;
    }
    float it = sigm_(acc[0]), ft = sigm_(acc[1]), gt = tanh_(acc[2]), ot = sigm_(acc[3]);
    c = ft * c + it * gt;
    h = ot * tanh_(c);

    // ---- normalize e_{t+1}
    float en;
    {
      float s1 = sm.embp[0][0] + sm.embp[1][0];
      float s2 = sm.embp[0][1] + sm.embp[1][1];
      float mn = s1 * 0.0078125f;
      float vr = fmaf(s2, 0.0078125f, -mn * mn);
      float inv = fast_rsq(vr + 1e-5f);
      en = (en_raw - mn) * inv * egg + ebt + pen;
    }

    // ---- epilogue partials for step t (consumed at next barrier 1)
    {
      float y = h + e;
      float ry0 = wave_sum(y), ry1 = wave_sum(y * y), ry2 = wave_sum(y * a_);
      if (L == 0) { sm.outp[w][0] = ry0; sm.outp[w][1] = ry1; sm.outp[w][2] = ry2; }
    }
    e = en;
  }

  __syncthreads();
  if (tid == 0) {
    float sy  = sm.outp[0][0] + sm.outp[1][0];
    float sy2 = sm.outp[0][1] + sm.outp[1][1];
    float sya = sm.outp[0][2] + sm.outp[1][2];
    float mn2 = sy * 0.0078125f;
    float vr2 = fmaf(sy2, 0.0078125f, -mn2 * mn2);
    float inv2 = fast_rsq(vr2 + 1e-5f);
    out[b * Tv + Tv - 1] = fmaf(inv2, sya - mn2 * SW, KB);
  }
}

extern "C" void kernel_launch(void* const* d_in, const int* in_sizes, int n_in,
                              void* d_out, int out_size, void* d_ws, size_t ws_size,
                              hipStream_t stream) {
  qlstm_kernel<<<dim3(1024), dim3(128), 0, stream>>>(
      (const float*)d_in[0],  (const float*)d_in[1],  (const float*)d_in[2],  (const float*)d_in[3],
      (const float*)d_in[4],  (const float*)d_in[5],  (const float*)d_in[6],  (const float*)d_in[7],
      (const float*)d_in[8],  (const float*)d_in[9],  (const float*)d_in[10], (const float*)d_in[11],
      (const float*)d_in[12], (const float*)d_in[13], (const float*)d_in[14], (const float*)d_in[15],
      (const float*)d_in[16], (const float*)d_in[17], (const float*)d_in[18], (const float*)d_in[19],
      (const float*)d_in[20], (const float*)d_in[21], (const float*)d_in[22], (const float*)d_in[23],
      (const float*)d_in[24], (const float*)d_in[25],
      (float*)d_out);
}